// Round 11
// baseline (470.342 us; speedup 1.0000x reference)
//
#include <hip/hip_runtime.h>
#include <hip/hip_cooperative_groups.h>

namespace cg = cooperative_groups;

#define EPS 1e-5f
#define SLOPE 0.2f
#define MAXK 512
#define SEGCAP 12288   // fixed segment stride; mean fill 8192
#define PBATCH 8192    // per partition block (1024 threads, 8 edges/thread)
#define AG1_SLOTS 8    // edges gathered per batch per node (LDS staging slots)
#define AG2_SLOTS 8

__device__ __forceinline__ float leaky(float z) {
    return fmaxf(z, 0.f) + SLOPE * fminf(z, 0.f);
}
__device__ __forceinline__ ushort f2bf(float f) {
    unsigned u = __float_as_uint(f);
    u += 0x7FFFu + ((u >> 16) & 1u);
    return (ushort)(u >> 16);
}
__device__ __forceinline__ float bf2f(ushort b) {
    return __uint_as_float(((unsigned)b) << 16);
}
__device__ __forceinline__ float blo(unsigned u) {
    return __uint_as_float(u << 16);
}
__device__ __forceinline__ float bhi(unsigned u) {
    return __uint_as_float(u & 0xffff0000u);
}
// async 16B gather to LDS: per-lane global src, wave-uniform LDS base,
// HW writes lane i at base + i*16. Zero VGPR destination cost.
__device__ __forceinline__ void gather16_to_lds(const void* g, void* l) {
    __builtin_amdgcn_global_load_lds(
        (const __attribute__((address_space(1))) void*)g,
        (__attribute__((address_space(3))) void*)l, 16, 0, 0);
}

// -- fused stage 1: [blocks 0..EB): edge partition] ∥ [blocks EB..: prep1] --
// (round-3 verified form: 1024 threads, PBATCH 8192, VGPR 32, ~66us)
__global__ __launch_bounds__(1024) void fused1(
    const int* __restrict__ ei, int E, int K, int* __restrict__ segcnt,
    unsigned* __restrict__ part,
    const float* __restrict__ x, const float* __restrict__ W1,
    const float* __restrict__ as1, const float* __restrict__ ad1,
    ushort* __restrict__ h1b, float* __restrict__ al_s, float* __restrict__ al_d,
    int N, int EB) {
    __shared__ float smem[4096 + 64 * 68];   // Ws | xs
    int t = threadIdx.x;
    if ((int)blockIdx.x < EB) {
        // ---------------- partition branch ----------------
        int* h   = (int*)smem;
        int* gp  = h + 512;
        int* run = h + 1024;
        for (int i = t; i < K; i += 1024) { h[i] = 0; run[i] = 0; }
        __syncthreads();
        int base = blockIdx.x * PBATCH;
        int sv[PBATCH / 1024], dv[PBATCH / 1024];
#pragma unroll
        for (int j = 0; j < PBATCH / 1024; j++) {
            int e = base + j * 1024 + t;
            sv[j] = (e < E) ? ei[e] : -1;
            dv[j] = (e < E) ? ei[E + e] : -1;
            if (dv[j] >= 0) atomicAdd(&h[dv[j] >> 8], 1);
        }
        __syncthreads();
        for (int i = t; i < K; i += 1024)
            gp[i] = h[i] ? atomicAdd(&segcnt[i * 16], h[i]) : 0;
        __syncthreads();
#pragma unroll
        for (int j = 0; j < PBATCH / 1024; j++) {
            if (dv[j] >= 0) {
                int b = dv[j] >> 8;
                int p = atomicAdd(&run[b], 1) + gp[b];
                if (p < SEGCAP)
                    part[(size_t)b * SEGCAP + p] =
                        ((unsigned)sv[j] << 8) | (unsigned)(dv[j] & 255);
            }
        }
        return;
    }
    // ---------------- prep1 branch: 64 rows/block ----------------
    float* Ws = smem;
    float (*xs)[68] = (float(*)[68])(smem + 4096);
    for (int i = t; i < 4096; i += 1024) Ws[i] = W1[i];
    int base = (blockIdx.x - EB) * 64;
    {
        int rr = t >> 4, kk = t & 15;
        int gr = base + rr;
        float4 vx = (gr < N) ? ((const float4*)x)[(size_t)gr * 16 + kk]
                             : make_float4(0.f, 0.f, 0.f, 0.f);
        *(float4*)&xs[rr][kk * 4] = vx;
    }
    __syncthreads();
    int wv = t >> 6, c = t & 63;
    int r0 = base + wv * 4;
    float acc0 = 0.f, acc1 = 0.f, acc2 = 0.f, acc3 = 0.f;
#pragma unroll
    for (int k = 0; k < 64; k += 4) {
        float4 x0 = *(const float4*)&xs[wv * 4 + 0][k];
        float4 x1 = *(const float4*)&xs[wv * 4 + 1][k];
        float4 x2 = *(const float4*)&xs[wv * 4 + 2][k];
        float4 x3 = *(const float4*)&xs[wv * 4 + 3][k];
        float w0 = Ws[(k + 0) * 64 + c];
        float w1 = Ws[(k + 1) * 64 + c];
        float w2 = Ws[(k + 2) * 64 + c];
        float w3 = Ws[(k + 3) * 64 + c];
        acc0 = fmaf(x0.x, w0, acc0); acc1 = fmaf(x1.x, w0, acc1);
        acc2 = fmaf(x2.x, w0, acc2); acc3 = fmaf(x3.x, w0, acc3);
        acc0 = fmaf(x0.y, w1, acc0); acc1 = fmaf(x1.y, w1, acc1);
        acc2 = fmaf(x2.y, w1, acc2); acc3 = fmaf(x3.y, w1, acc3);
        acc0 = fmaf(x0.z, w2, acc0); acc1 = fmaf(x1.z, w2, acc1);
        acc2 = fmaf(x2.z, w2, acc2); acc3 = fmaf(x3.z, w2, acc3);
        acc0 = fmaf(x0.w, w3, acc0); acc1 = fmaf(x1.w, w3, acc1);
        acc2 = fmaf(x2.w, w3, acc2); acc3 = fmaf(x3.w, w3, acc3);
    }
    int head = c >> 5, cc = c & 31;
    float asc = as1[head * 32 + cc], adc = ad1[head * 32 + cc];
    float vs0 = acc0 * asc, vd0 = acc0 * adc;
    float vs1 = acc1 * asc, vd1 = acc1 * adc;
    float vs2 = acc2 * asc, vd2 = acc2 * adc;
    float vs3 = acc3 * asc, vd3 = acc3 * adc;
#pragma unroll
    for (int off = 1; off < 32; off <<= 1) {
        vs0 += __shfl_xor(vs0, off); vd0 += __shfl_xor(vd0, off);
        vs1 += __shfl_xor(vs1, off); vd1 += __shfl_xor(vd1, off);
        vs2 += __shfl_xor(vs2, off); vd2 += __shfl_xor(vd2, off);
        vs3 += __shfl_xor(vs3, off); vd3 += __shfl_xor(vd3, off);
    }
    if (r0 + 0 < N) h1b[(size_t)(r0 + 0) * 64 + c] = f2bf(acc0);
    if (r0 + 1 < N) h1b[(size_t)(r0 + 1) * 64 + c] = f2bf(acc1);
    if (r0 + 2 < N) h1b[(size_t)(r0 + 2) * 64 + c] = f2bf(acc2);
    if (r0 + 3 < N) h1b[(size_t)(r0 + 3) * 64 + c] = f2bf(acc3);
    if (cc == 0) {
        if (r0 + 0 < N) { al_s[(r0 + 0) * 2 + head] = vs0; al_d[(r0 + 0) * 2 + head] = vd0; }
        if (r0 + 1 < N) { al_s[(r0 + 1) * 2 + head] = vs1; al_d[(r0 + 1) * 2 + head] = vd1; }
        if (r0 + 2 < N) { al_s[(r0 + 2) * 2 + head] = vs2; al_d[(r0 + 2) * 2 + head] = vd2; }
        if (r0 + 3 < N) { al_s[(r0 + 3) * 2 + head] = vs3; al_d[(r0 + 3) * 2 + head] = vd3; }
    }
}

// -- stage 2: per-segment LDS counting sort (wave-scan version, round-9) ----
__global__ __launch_bounds__(1024) void sortseg(
    const int* __restrict__ segcnt, int N,
    unsigned* __restrict__ part, int* __restrict__ nodeofs, int* __restrict__ cnt,
    int* __restrict__ perm) {
    __shared__ int h2[4096];
    __shared__ int ex[256];
    __shared__ int wsum[4];
    __shared__ unsigned outb[SEGCAP];
    int b = blockIdx.x, t = threadIdx.x;
    int lane = t & 63;
    size_t base = (size_t)b * SEGCAP;
    int sz = min(segcnt[b * 16], SEGCAP);
    for (int i = t; i < 4096; i += 1024) h2[i] = 0;
    __syncthreads();
    for (int i = t; i < sz; i += 1024) {
        unsigned code = part[base + i];
        int key = ((code & 255) << 4) | ((code >> 21) & 15);
        atomicAdd(&h2[key], 1);
    }
    __syncthreads();
    int v = 0;
    if (t < 256) {
#pragma unroll
        for (int i = 0; i < 16; i++) v += h2[t * 16 + i];
    }
    int incl = v;
#pragma unroll
    for (int off = 1; off < 64; off <<= 1) {
        int y = __shfl_up(incl, off);
        if (lane >= off) incl += y;
    }
    if (t < 256 && lane == 63) wsum[t >> 6] = incl;
    __syncthreads();
    if (t < 256) {
        int w = t >> 6;
        int wpre = 0;
#pragma unroll
        for (int k = 0; k < 4; k++) if (k < w) wpre += wsum[k];
        int exv = incl + wpre - v;       // exclusive prefix
        int run = exv;
#pragma unroll
        for (int i = 0; i < 16; i++) {
            int lc = h2[t * 16 + i];
            h2[t * 16 + i] = run;
            run += lc;
        }
        int n = b * 256 + t;
        if (n < N) { cnt[n] = v; nodeofs[n] = (int)(base + exv); }
    }
    __syncthreads();
    for (int i = t; i < sz; i += 1024) {
        unsigned code = part[base + i];
        int key = ((code & 255) << 4) | ((code >> 21) & 15);
        int p = atomicAdd(&h2[key], 1);
        outb[p] = code >> 8;          // src
    }
    __syncthreads();
    for (int i = t; i < sz; i += 1024) part[base + i] = outb[i];
    // ---- segment-local degree sort -> perm (lanes < 256) ----
    __syncthreads();
    if (t < 256) h2[t] = 0;
    __syncthreads();
    int n = b * 256 + t;
    int dbin = min(v, 255);
    if (t < 256 && n < N) atomicAdd(&h2[dbin], 1);
    __syncthreads();
    int hv = (t < 256) ? h2[t] : 0;
    int incl2 = hv;
#pragma unroll
    for (int off = 1; off < 64; off <<= 1) {
        int y = __shfl_up(incl2, off);
        if (lane >= off) incl2 += y;
    }
    if (t < 256 && lane == 63) wsum[t >> 6] = incl2;
    __syncthreads();
    if (t < 256) {
        int w = t >> 6;
        int wpre = 0;
#pragma unroll
        for (int k = 0; k < 4; k++) if (k < w) wpre += wsum[k];
        ex[t] = incl2 + wpre - hv;       // exclusive prefix
    }
    __syncthreads();
    if (t < 256 && n < N) {
        int r = atomicAdd(&ex[dbin], 1);
        perm[b * 256 + r] = n;
    }
}

// ---- shared body: layer1 aggregation + LN + ELU + fused prep2 GEMM --------
// (round-8 verified logic; tile = 32-node output tile index)
__device__ __forceinline__ void agg1_body(
    int tile, uint4* stageAll, const float* W2s,
    const ushort* __restrict__ h1b, const float* __restrict__ als,
    const float* __restrict__ ald, const int* __restrict__ nodeofs,
    const int* __restrict__ cnt, const unsigned* __restrict__ csr,
    const int* __restrict__ perm, const float* __restrict__ b1,
    const float* __restrict__ g1, const float* __restrict__ bb1,
    const float* __restrict__ as2, const float* __restrict__ ad2,
    ushort* __restrict__ h2b, float* __restrict__ al2s,
    float* __restrict__ al2d, int N) {
    int t = threadIdx.x;
    int wid = t >> 6, lane = t & 63;
    int grp = lane >> 3, q = lane & 7;        // 8 lanes per node
    int gbase = grp << 3;
    uint4* mystage = stageAll + wid * (AG1_SLOTS * 64);
    int idx = tile * 32 + wid * 8 + grp;
    bool valid = idx < N;
    int nc = perm[min(idx, N - 1)];
    int head = q >> 2;
    const float2* als2 = (const float2*)als;
    const float2* ald2 = (const float2*)ald;
    float2 adv = ald2[nc], asv = als2[nc];
    float ad0 = adv.x, ad1v = adv.y;
    float wsf = __expf(leaky((head ? asv.y : asv.x) + (head ? ad1v : ad0)));
    const uint4* h4 = (const uint4*)h1b;
    uint4 hs = h4[(size_t)nc * 8 + q];
    float a0 = wsf * blo(hs.x), a1 = wsf * bhi(hs.x);
    float a2 = wsf * blo(hs.y), a3 = wsf * bhi(hs.y);
    float a4 = wsf * blo(hs.z), a5 = wsf * bhi(hs.z);
    float a6 = wsf * blo(hs.w), a7 = wsf * bhi(hs.w);
    float lp0 = 0.f, lp1 = 0.f;
    int ofs = valid ? nodeofs[nc] : 0;
    int deg = valid ? cnt[nc] : 0;
    int degm1 = max(deg - 1, 0);
    int degmax = deg;
    degmax = max(degmax, __shfl_xor(degmax, 8));
    degmax = max(degmax, __shfl_xor(degmax, 16));
    degmax = max(degmax, __shfl_xor(degmax, 32));
    int sq = 0;
    if (degmax > 0) sq = min((int)csr[ofs + min(q, degm1)], N - 1);
    for (int eb = 0; eb < degmax; eb += AG1_SLOTS) {
#pragma unroll
        for (int k = 0; k < AG1_SLOTS; k++) {
            int s = __shfl(sq, gbase + k);
            gather16_to_lds(h4 + ((size_t)s * 8 + q), &mystage[k * 64]);
        }
        float2 av = als2[sq];
        int nsq = sq;
        int ebn = eb + AG1_SLOTS;
        if (ebn < degmax)
            nsq = min((int)csr[ofs + min(ebn + q, degm1)], N - 1);
        bool ev = (eb + q < deg);
        float w0 = ev ? __expf(leaky(av.x + ad0)) : 0.f;
        float w1 = ev ? __expf(leaky(av.y + ad1v)) : 0.f;
        lp0 += w0;
        lp1 += w1;
        asm volatile("s_waitcnt vmcnt(0)" ::: "memory");
        __builtin_amdgcn_sched_barrier(0);
#pragma unroll
        for (int k = 0; k < AG1_SLOTS; k++) {
            float wk0 = __shfl(w0, gbase + k);
            float wk1 = __shfl(w1, gbase + k);
            float w = head ? wk1 : wk0;
            uint4 hv = mystage[k * 64 + lane];
            a0 = fmaf(w, blo(hv.x), a0); a1 = fmaf(w, bhi(hv.x), a1);
            a2 = fmaf(w, blo(hv.y), a2); a3 = fmaf(w, bhi(hv.y), a3);
            a4 = fmaf(w, blo(hv.z), a4); a5 = fmaf(w, bhi(hv.z), a5);
            a6 = fmaf(w, blo(hv.w), a6); a7 = fmaf(w, bhi(hv.w), a7);
        }
        sq = nsq;
    }
#pragma unroll
    for (int off = 1; off < 8; off <<= 1) {
        lp0 += __shfl_xor(lp0, off);
        lp1 += __shfl_xor(lp1, off);
    }
    if (!valid) return;
    float l = (head ? lp1 : lp0) + wsf;
    float inv = 1.f / l;
    float4 bA = ((const float4*)b1)[2 * q];
    float4 bB = ((const float4*)b1)[2 * q + 1];
    float v0 = a0 * inv + bA.x, v1 = a1 * inv + bA.y;
    float v2 = a2 * inv + bA.z, v3 = a3 * inv + bA.w;
    float v4 = a4 * inv + bB.x, v5 = a5 * inv + bB.y;
    float v6 = a6 * inv + bB.z, v7 = a7 * inv + bB.w;
    float s1 = v0 + v1 + v2 + v3 + v4 + v5 + v6 + v7;
#pragma unroll
    for (int off = 1; off < 8; off <<= 1) s1 += __shfl_xor(s1, off);
    float mu = s1 * (1.f / 64.f);
    float d0 = v0 - mu, d1 = v1 - mu, d2 = v2 - mu, d3 = v3 - mu;
    float d4 = v4 - mu, d5 = v5 - mu, d6 = v6 - mu, d7 = v7 - mu;
    float s2v = d0 * d0 + d1 * d1 + d2 * d2 + d3 * d3
              + d4 * d4 + d5 * d5 + d6 * d6 + d7 * d7;
#pragma unroll
    for (int off = 1; off < 8; off <<= 1) s2v += __shfl_xor(s2v, off);
    float rs = rsqrtf(s2v * (1.f / 64.f) + EPS);
    float4 gA = ((const float4*)g1)[2 * q];
    float4 gB = ((const float4*)g1)[2 * q + 1];
    float4 cA = ((const float4*)bb1)[2 * q];
    float4 cB = ((const float4*)bb1)[2 * q + 1];
    float ya[8];
    ya[0] = d0 * rs * gA.x + cA.x;
    ya[1] = d1 * rs * gA.y + cA.y;
    ya[2] = d2 * rs * gA.z + cA.z;
    ya[3] = d3 * rs * gA.w + cA.w;
    ya[4] = d4 * rs * gB.x + cB.x;
    ya[5] = d5 * rs * gB.y + cB.y;
    ya[6] = d6 * rs * gB.z + cB.z;
    ya[7] = d7 * rs * gB.w + cB.w;
#pragma unroll
    for (int j = 0; j < 8; j++)
        ya[j] = (ya[j] > 0.f) ? ya[j] : (__expf(ya[j]) - 1.f);
    float o0 = 0.f, o1 = 0.f, o2 = 0.f, o3 = 0.f;
#pragma unroll
    for (int src = 0; src < 8; src++) {
#pragma unroll
        for (int j = 0; j < 8; j++) {
            float yv = __shfl(ya[j], gbase + src);
            float4 wr = *(const float4*)&W2s[(src * 8 + j) * 32 + 4 * q];
            o0 = fmaf(yv, wr.x, o0);
            o1 = fmaf(yv, wr.y, o1);
            o2 = fmaf(yv, wr.z, o2);
            o3 = fmaf(yv, wr.w, o3);
        }
    }
    ((ushort4*)h2b)[(size_t)nc * 8 + q] =
        make_ushort4(f2bf(o0), f2bf(o1), f2bf(o2), f2bf(o3));
    float4 a2v = ((const float4*)as2)[q];
    float4 d2v = ((const float4*)ad2)[q];
    float ps = o0 * a2v.x + o1 * a2v.y + o2 * a2v.z + o3 * a2v.w;
    float pd = o0 * d2v.x + o1 * d2v.y + o2 * d2v.z + o3 * d2v.w;
    ps += __shfl_xor(ps, 1); ps += __shfl_xor(ps, 2); ps += __shfl_xor(ps, 4);
    pd += __shfl_xor(pd, 1); pd += __shfl_xor(pd, 2); pd += __shfl_xor(pd, 4);
    if (q == 0) { al2s[nc] = ps; al2d[nc] = pd; }
}

// ---- shared body: layer2 aggregation (async LDS, 4 lanes/node) ------------
__device__ __forceinline__ void agg2_body(
    int tile, uint4* stageAll,
    const ushort* __restrict__ h2b, const float* __restrict__ als,
    const float* __restrict__ ald, const int* __restrict__ nodeofs,
    const int* __restrict__ cnt, const unsigned* __restrict__ csr,
    const int* __restrict__ perm,
    const float* __restrict__ b2, const float* __restrict__ g2,
    const float* __restrict__ bb2, const float* __restrict__ Wout,
    const float* __restrict__ bout, float* __restrict__ out, int N) {
    int t = threadIdx.x;
    int wid = t >> 6, lane = t & 63;
    int grp = lane >> 2, q = lane & 3;        // 4 lanes per node
    int gbase = grp << 2;
    uint4* mystage = stageAll + wid * (AG2_SLOTS * 64);
    int idx = tile * 64 + wid * 16 + grp;
    bool valid = idx < N;
    int nc = perm[min(idx, N - 1)];
    float myad = ald[nc];
    float wsf = __expf(leaky(als[nc] + myad));
    const uint4* h4 = (const uint4*)h2b;
    uint4 hs = h4[(size_t)nc * 4 + q];
    float a0 = wsf * blo(hs.x), a1 = wsf * bhi(hs.x);
    float a2 = wsf * blo(hs.y), a3 = wsf * bhi(hs.y);
    float a4 = wsf * blo(hs.z), a5 = wsf * bhi(hs.z);
    float a6 = wsf * blo(hs.w), a7 = wsf * bhi(hs.w);
    float lp = 0.f;
    int ofs = valid ? nodeofs[nc] : 0;
    int deg = valid ? cnt[nc] : 0;
    int degm1 = max(deg - 1, 0);
    int degmax = deg;
    degmax = max(degmax, __shfl_xor(degmax, 4));
    degmax = max(degmax, __shfl_xor(degmax, 8));
    degmax = max(degmax, __shfl_xor(degmax, 16));
    degmax = max(degmax, __shfl_xor(degmax, 32));
    int sq0 = 0, sq1 = 0;
    if (degmax > 0) {
        sq0 = min((int)csr[ofs + min(q, degm1)], N - 1);
        sq1 = min((int)csr[ofs + min(4 + q, degm1)], N - 1);
    }
    for (int eb = 0; eb < degmax; eb += AG2_SLOTS) {
#pragma unroll
        for (int k = 0; k < AG2_SLOTS; k++) {
            int s = (k < 4) ? __shfl(sq0, gbase + k)
                            : __shfl(sq1, gbase + (k - 4));
            gather16_to_lds(h4 + ((size_t)s * 4 + q), &mystage[k * 64]);
        }
        float av0 = als[sq0];
        float av1 = als[sq1];
        int nsq0 = sq0, nsq1 = sq1;
        int ebn = eb + AG2_SLOTS;
        if (ebn < degmax) {
            nsq0 = min((int)csr[ofs + min(ebn + q, degm1)], N - 1);
            nsq1 = min((int)csr[ofs + min(ebn + 4 + q, degm1)], N - 1);
        }
        float wq0 = (eb + q < deg) ? __expf(leaky(av0 + myad)) : 0.f;
        float wq1 = (eb + 4 + q < deg) ? __expf(leaky(av1 + myad)) : 0.f;
        lp += wq0 + wq1;
        asm volatile("s_waitcnt vmcnt(0)" ::: "memory");
        __builtin_amdgcn_sched_barrier(0);
#pragma unroll
        for (int k = 0; k < AG2_SLOTS; k++) {
            float w = (k < 4) ? __shfl(wq0, gbase + k)
                              : __shfl(wq1, gbase + (k - 4));
            uint4 hv = mystage[k * 64 + lane];
            a0 = fmaf(w, blo(hv.x), a0); a1 = fmaf(w, bhi(hv.x), a1);
            a2 = fmaf(w, blo(hv.y), a2); a3 = fmaf(w, bhi(hv.y), a3);
            a4 = fmaf(w, blo(hv.z), a4); a5 = fmaf(w, bhi(hv.z), a5);
            a6 = fmaf(w, blo(hv.w), a6); a7 = fmaf(w, bhi(hv.w), a7);
        }
        sq0 = nsq0;
        sq1 = nsq1;
    }
    lp += __shfl_xor(lp, 1);
    lp += __shfl_xor(lp, 2);
    if (!valid) return;
    float l = lp + wsf;
    float inv = 1.f / l;
    float4 bA = ((const float4*)b2)[2 * q];
    float4 bB = ((const float4*)b2)[2 * q + 1];
    float v0 = a0 * inv + bA.x, v1 = a1 * inv + bA.y;
    float v2 = a2 * inv + bA.z, v3 = a3 * inv + bA.w;
    float v4 = a4 * inv + bB.x, v5 = a5 * inv + bB.y;
    float v6 = a6 * inv + bB.z, v7 = a7 * inv + bB.w;
    float s1 = v0 + v1 + v2 + v3 + v4 + v5 + v6 + v7;
    s1 += __shfl_xor(s1, 1); s1 += __shfl_xor(s1, 2);
    float mu = s1 * (1.f / 32.f);
    float d0 = v0 - mu, d1 = v1 - mu, d2 = v2 - mu, d3 = v3 - mu;
    float d4 = v4 - mu, d5 = v5 - mu, d6 = v6 - mu, d7 = v7 - mu;
    float s2v = d0 * d0 + d1 * d1 + d2 * d2 + d3 * d3
              + d4 * d4 + d5 * d5 + d6 * d6 + d7 * d7;
    s2v += __shfl_xor(s2v, 1); s2v += __shfl_xor(s2v, 2);
    float rs = rsqrtf(s2v * (1.f / 32.f) + EPS);
    float4 gA = ((const float4*)g2)[2 * q];
    float4 gB = ((const float4*)g2)[2 * q + 1];
    float4 cA = ((const float4*)bb2)[2 * q];
    float4 cB = ((const float4*)bb2)[2 * q + 1];
    float y0 = d0 * rs * gA.x + cA.x;
    float y1 = d1 * rs * gA.y + cA.y;
    float y2 = d2 * rs * gA.z + cA.z;
    float y3 = d3 * rs * gA.w + cA.w;
    float y4 = d4 * rs * gB.x + cB.x;
    float y5 = d5 * rs * gB.y + cB.y;
    float y6 = d6 * rs * gB.z + cB.z;
    float y7 = d7 * rs * gB.w + cB.w;
    y0 = (y0 > 0.f) ? y0 : (__expf(y0) - 1.f);
    y1 = (y1 > 0.f) ? y1 : (__expf(y1) - 1.f);
    y2 = (y2 > 0.f) ? y2 : (__expf(y2) - 1.f);
    y3 = (y3 > 0.f) ? y3 : (__expf(y3) - 1.f);
    y4 = (y4 > 0.f) ? y4 : (__expf(y4) - 1.f);
    y5 = (y5 > 0.f) ? y5 : (__expf(y5) - 1.f);
    y6 = (y6 > 0.f) ? y6 : (__expf(y6) - 1.f);
    y7 = (y7 > 0.f) ? y7 : (__expf(y7) - 1.f);
    float4 wA = ((const float4*)Wout)[2 * q];
    float4 wB = ((const float4*)Wout)[2 * q + 1];
    float p = y0 * wA.x + y1 * wA.y + y2 * wA.z + y3 * wA.w
            + y4 * wB.x + y5 * wB.y + y6 * wB.z + y7 * wB.w;
    p += __shfl_xor(p, 1); p += __shfl_xor(p, 2);
    if (q == 0) out[nc] = p + bout[0];
}

// ---- standalone kernels (fallback path, identical to round-10) ------------
__global__ __launch_bounds__(256) void aggB1(
    const ushort* __restrict__ h1b, const float* __restrict__ als,
    const float* __restrict__ ald, const int* __restrict__ nodeofs,
    const int* __restrict__ cnt, const unsigned* __restrict__ csr,
    const int* __restrict__ perm,
    const float* __restrict__ b1, const float* __restrict__ g1,
    const float* __restrict__ bb1,
    const float* __restrict__ W2, const float* __restrict__ as2,
    const float* __restrict__ ad2, ushort* __restrict__ h2b,
    float* __restrict__ al2s, float* __restrict__ al2d, int N) {
    __shared__ uint4 stage[4 * AG1_SLOTS * 64];
    __shared__ float W2s[64 * 32];
    int t = threadIdx.x;
    for (int i = t; i < 2048; i += 256) W2s[i] = W2[i];
    __syncthreads();
    agg1_body(blockIdx.x, stage, W2s, h1b, als, ald, nodeofs, cnt, csr, perm,
              b1, g1, bb1, as2, ad2, h2b, al2s, al2d, N);
}

__global__ __launch_bounds__(256) void aggB2(
    const ushort* __restrict__ h2b, const float* __restrict__ als,
    const float* __restrict__ ald, const int* __restrict__ nodeofs,
    const int* __restrict__ cnt, const unsigned* __restrict__ csr,
    const int* __restrict__ perm,
    const float* __restrict__ b2, const float* __restrict__ g2,
    const float* __restrict__ bb2, const float* __restrict__ Wout,
    const float* __restrict__ bout, float* __restrict__ out, int N) {
    __shared__ uint4 stage[4 * AG2_SLOTS * 64];
    agg2_body(blockIdx.x, stage, h2b, als, ald, nodeofs, cnt, csr, perm,
              b2, g2, bb2, Wout, bout, out, N);
}

// ---- cooperative fused tail: aggB1 phase -> grid.sync -> aggB2 phase ------
// 1024 blocks x 256 thr; LDS 40KB -> 4 blocks/CU x 256 CU = 1024 co-resident.
__global__ __launch_bounds__(256, 4) void tail2(
    const ushort* __restrict__ h1b, const float* __restrict__ als1,
    const float* __restrict__ ald1, const int* __restrict__ nodeofs,
    const int* __restrict__ cnt, const unsigned* __restrict__ csr,
    const int* __restrict__ perm, const float* __restrict__ b1,
    const float* __restrict__ g1, const float* __restrict__ bb1,
    const float* __restrict__ W2, const float* __restrict__ as2,
    const float* __restrict__ ad2, ushort* __restrict__ h2b,
    float* __restrict__ al2s, float* __restrict__ al2d,
    const float* __restrict__ b2, const float* __restrict__ g2,
    const float* __restrict__ bb2, const float* __restrict__ Wout,
    const float* __restrict__ bout, float* __restrict__ out, int N) {
    __shared__ uint4 stage[4 * AG1_SLOTS * 64];   // 32 KB (shared by phases)
    __shared__ float W2s[64 * 32];                // 8 KB
    cg::grid_group grid = cg::this_grid();
    int t = threadIdx.x;
    for (int i = t; i < 2048; i += 256) W2s[i] = W2[i];
    __syncthreads();
    const int nT1 = (N + 31) / 32;
    for (int tile = blockIdx.x; tile < nT1; tile += gridDim.x)
        agg1_body(tile, stage, W2s, h1b, als1, ald1, nodeofs, cnt, csr, perm,
                  b1, g1, bb1, as2, ad2, h2b, al2s, al2d, N);
    grid.sync();
    const int nT2 = (N + 63) / 64;
    for (int tile = blockIdx.x; tile < nT2; tile += gridDim.x)
        agg2_body(tile, stage, h2b, al2s, al2d, nodeofs, cnt, csr, perm,
                  b2, g2, bb2, Wout, bout, out, N);
}

extern "C" void kernel_launch(void* const* d_in, const int* in_sizes, int n_in,
                              void* d_out, int out_size, void* d_ws, size_t ws_size,
                              hipStream_t stream) {
    const float* x    = (const float*)d_in[0];
    const int*   ei   = (const int*)d_in[1];
    const float* W1   = (const float*)d_in[2];
    const float* as1  = (const float*)d_in[3];
    const float* ad1  = (const float*)d_in[4];
    const float* b1   = (const float*)d_in[5];
    const float* g1   = (const float*)d_in[6];
    const float* bb1  = (const float*)d_in[7];
    const float* W2   = (const float*)d_in[8];
    const float* as2  = (const float*)d_in[9];
    const float* ad2  = (const float*)d_in[10];
    const float* b2   = (const float*)d_in[11];
    const float* g2   = (const float*)d_in[12];
    const float* bb2  = (const float*)d_in[13];
    const float* Wout = (const float*)d_in[14];
    const float* bout = (const float*)d_in[15];
    float* out = (float*)d_out;

    int N = in_sizes[0] / 64;
    const int E = in_sizes[1] / 2;
    const int K = (N + 255) / 256;   // segments (<= MAXK)

    auto align_up = [](size_t v) { return (v + 255) & ~(size_t)255; };
    char* ws = (char*)d_ws;
    unsigned* part    = (unsigned*)ws; ws += align_up((size_t)K * SEGCAP * 4);
    int*      segcnt  = (int*)ws;      ws += align_up((size_t)MAXK * 16 * 4);
    int*      nodeofs = (int*)ws;      ws += align_up((size_t)N * 4);
    int*      cnt     = (int*)ws;      ws += align_up((size_t)N * 4);
    int*      perm    = (int*)ws;      ws += align_up((size_t)(K * 256) * 4);
    ushort*   h1b     = (ushort*)ws;   ws += align_up((size_t)N * 64 * 2);
    ushort*   h2b     = (ushort*)ws;   ws += align_up((size_t)N * 32 * 2);
    float*    al1s    = (float*)ws;    ws += align_up((size_t)N * 2 * 4);
    float*    al1d    = (float*)ws;    ws += align_up((size_t)N * 2 * 4);
    float*    al2s    = (float*)ws;    ws += align_up((size_t)N * 4);
    float*    al2d    = (float*)ws;    ws += align_up((size_t)N * 4);

    const int EB = (E + PBATCH - 1) / PBATCH;
    const int PB = (N + 63) / 64;

    hipMemsetAsync(segcnt, 0, (size_t)K * 16 * 4, stream);
    fused1<<<EB + PB, 1024, 0, stream>>>(ei, E, K, segcnt, part,
                                         x, W1, as1, ad1, h1b, al1s, al1d, N, EB);
    sortseg<<<K, 1024, 0, stream>>>(segcnt, N, part, nodeofs, cnt, perm);

    // cooperative fused tail with error-checked fallback (round-5 lesson)
    const ushort* h1b_c = h1b;
    const float* al1s_c = al1s;
    const float* al1d_c = al1d;
    const int* nodeofs_c = nodeofs;
    const int* cnt_c = cnt;
    const unsigned* csr_c = part;
    const int* perm_c = perm;
    ushort* h2b_c = h2b;
    float* al2s_c = al2s;
    float* al2d_c = al2d;
    void* args[] = {
        (void*)&h1b_c, (void*)&al1s_c, (void*)&al1d_c, (void*)&nodeofs_c,
        (void*)&cnt_c, (void*)&csr_c, (void*)&perm_c, (void*)&b1,
        (void*)&g1, (void*)&bb1, (void*)&W2, (void*)&as2, (void*)&ad2,
        (void*)&h2b_c, (void*)&al2s_c, (void*)&al2d_c,
        (void*)&b2, (void*)&g2, (void*)&bb2, (void*)&Wout,
        (void*)&bout, (void*)&out, (void*)&N
    };
    hipError_t err = hipLaunchCooperativeKernel(
        (const void*)tail2, dim3(1024), dim3(256), args, 0, stream);
    if (err != hipSuccess) {
        aggB1<<<(N + 31) / 32, 256, 0, stream>>>(
            h1b, al1s, al1d, nodeofs, cnt, part, perm, b1, g1, bb1,
            W2, as2, ad2, h2b, al2s, al2d, N);
        aggB2<<<(N + 63) / 64, 256, 0, stream>>>(
            h2b, al2s, al2d, nodeofs, cnt, part, perm,
            b2, g2, bb2, Wout, bout, out, N);
    }
}

// Round 13
// 296.412 us; speedup vs baseline: 1.5868x; 1.5868x over previous
//
#include <hip/hip_runtime.h>

#define EPS 1e-5f
#define SLOPE 0.2f
#define MAXK 512
#define SEGCAP 12288   // fixed segment stride; mean fill 8192
#define PBATCH 8192    // per partition block (1024 threads, 8 edges/thread)
#define AG1_SLOTS 8    // edges gathered per batch per node (LDS staging slots)

__device__ __forceinline__ float leaky(float z) {
    return fmaxf(z, 0.f) + SLOPE * fminf(z, 0.f);
}
__device__ __forceinline__ ushort f2bf(float f) {
    unsigned u = __float_as_uint(f);
    u += 0x7FFFu + ((u >> 16) & 1u);
    return (ushort)(u >> 16);
}
__device__ __forceinline__ float bf2f(ushort b) {
    return __uint_as_float(((unsigned)b) << 16);
}
__device__ __forceinline__ float blo(unsigned u) {
    return __uint_as_float(u << 16);
}
__device__ __forceinline__ float bhi(unsigned u) {
    return __uint_as_float(u & 0xffff0000u);
}
// async 16B gather to LDS: per-lane global src, wave-uniform LDS base,
// HW writes lane i at base + i*16. Zero VGPR destination cost.
__device__ __forceinline__ void gather16_to_lds(const void* g, void* l) {
    __builtin_amdgcn_global_load_lds(
        (const __attribute__((address_space(1))) void*)g,
        (__attribute__((address_space(3))) void*)l, 16, 0, 0);
}

// -- fused stage 1: [blocks 0..EB): edge partition] ∥ [blocks EB..: prep1] --
// (round-3 verified form: 1024 threads, PBATCH 8192, VGPR 32, ~66us)
__global__ __launch_bounds__(1024) void fused1(
    const int* __restrict__ ei, int E, int K, int* __restrict__ segcnt,
    unsigned* __restrict__ part,
    const float* __restrict__ x, const float* __restrict__ W1,
    const float* __restrict__ as1, const float* __restrict__ ad1,
    ushort* __restrict__ h1b, float* __restrict__ al_s, float* __restrict__ al_d,
    int N, int EB) {
    __shared__ float smem[4096 + 64 * 68];   // Ws | xs
    int t = threadIdx.x;
    if ((int)blockIdx.x < EB) {
        // ---------------- partition branch ----------------
        int* h   = (int*)smem;
        int* gp  = h + 512;
        int* run = h + 1024;
        for (int i = t; i < K; i += 1024) { h[i] = 0; run[i] = 0; }
        __syncthreads();
        int base = blockIdx.x * PBATCH;
        int sv[PBATCH / 1024], dv[PBATCH / 1024];
#pragma unroll
        for (int j = 0; j < PBATCH / 1024; j++) {
            int e = base + j * 1024 + t;
            sv[j] = (e < E) ? ei[e] : -1;
            dv[j] = (e < E) ? ei[E + e] : -1;
            if (dv[j] >= 0) atomicAdd(&h[dv[j] >> 8], 1);
        }
        __syncthreads();
        for (int i = t; i < K; i += 1024)
            gp[i] = h[i] ? atomicAdd(&segcnt[i * 16], h[i]) : 0;
        __syncthreads();
#pragma unroll
        for (int j = 0; j < PBATCH / 1024; j++) {
            if (dv[j] >= 0) {
                int b = dv[j] >> 8;
                int p = atomicAdd(&run[b], 1) + gp[b];
                if (p < SEGCAP)
                    part[(size_t)b * SEGCAP + p] =
                        ((unsigned)sv[j] << 8) | (unsigned)(dv[j] & 255);
            }
        }
        return;
    }
    // ---------------- prep1 branch: 64 rows/block ----------------
    float* Ws = smem;
    float (*xs)[68] = (float(*)[68])(smem + 4096);
    for (int i = t; i < 4096; i += 1024) Ws[i] = W1[i];
    int base = (blockIdx.x - EB) * 64;
    {
        int rr = t >> 4, kk = t & 15;
        int gr = base + rr;
        float4 vx = (gr < N) ? ((const float4*)x)[(size_t)gr * 16 + kk]
                             : make_float4(0.f, 0.f, 0.f, 0.f);
        *(float4*)&xs[rr][kk * 4] = vx;
    }
    __syncthreads();
    int wv = t >> 6, c = t & 63;
    int r0 = base + wv * 4;
    float acc0 = 0.f, acc1 = 0.f, acc2 = 0.f, acc3 = 0.f;
#pragma unroll
    for (int k = 0; k < 64; k += 4) {
        float4 x0 = *(const float4*)&xs[wv * 4 + 0][k];
        float4 x1 = *(const float4*)&xs[wv * 4 + 1][k];
        float4 x2 = *(const float4*)&xs[wv * 4 + 2][k];
        float4 x3 = *(const float4*)&xs[wv * 4 + 3][k];
        float w0 = Ws[(k + 0) * 64 + c];
        float w1 = Ws[(k + 1) * 64 + c];
        float w2 = Ws[(k + 2) * 64 + c];
        float w3 = Ws[(k + 3) * 64 + c];
        acc0 = fmaf(x0.x, w0, acc0); acc1 = fmaf(x1.x, w0, acc1);
        acc2 = fmaf(x2.x, w0, acc2); acc3 = fmaf(x3.x, w0, acc3);
        acc0 = fmaf(x0.y, w1, acc0); acc1 = fmaf(x1.y, w1, acc1);
        acc2 = fmaf(x2.y, w1, acc2); acc3 = fmaf(x3.y, w1, acc3);
        acc0 = fmaf(x0.z, w2, acc0); acc1 = fmaf(x1.z, w2, acc1);
        acc2 = fmaf(x2.z, w2, acc2); acc3 = fmaf(x3.z, w2, acc3);
        acc0 = fmaf(x0.w, w3, acc0); acc1 = fmaf(x1.w, w3, acc1);
        acc2 = fmaf(x2.w, w3, acc2); acc3 = fmaf(x3.w, w3, acc3);
    }
    int head = c >> 5, cc = c & 31;
    float asc = as1[head * 32 + cc], adc = ad1[head * 32 + cc];
    float vs0 = acc0 * asc, vd0 = acc0 * adc;
    float vs1 = acc1 * asc, vd1 = acc1 * adc;
    float vs2 = acc2 * asc, vd2 = acc2 * adc;
    float vs3 = acc3 * asc, vd3 = acc3 * adc;
#pragma unroll
    for (int off = 1; off < 32; off <<= 1) {
        vs0 += __shfl_xor(vs0, off); vd0 += __shfl_xor(vd0, off);
        vs1 += __shfl_xor(vs1, off); vd1 += __shfl_xor(vd1, off);
        vs2 += __shfl_xor(vs2, off); vd2 += __shfl_xor(vd2, off);
        vs3 += __shfl_xor(vs3, off); vd3 += __shfl_xor(vd3, off);
    }
    if (r0 + 0 < N) h1b[(size_t)(r0 + 0) * 64 + c] = f2bf(acc0);
    if (r0 + 1 < N) h1b[(size_t)(r0 + 1) * 64 + c] = f2bf(acc1);
    if (r0 + 2 < N) h1b[(size_t)(r0 + 2) * 64 + c] = f2bf(acc2);
    if (r0 + 3 < N) h1b[(size_t)(r0 + 3) * 64 + c] = f2bf(acc3);
    if (cc == 0) {
        if (r0 + 0 < N) { al_s[(r0 + 0) * 2 + head] = vs0; al_d[(r0 + 0) * 2 + head] = vd0; }
        if (r0 + 1 < N) { al_s[(r0 + 1) * 2 + head] = vs1; al_d[(r0 + 1) * 2 + head] = vd1; }
        if (r0 + 2 < N) { al_s[(r0 + 2) * 2 + head] = vs2; al_d[(r0 + 2) * 2 + head] = vd2; }
        if (r0 + 3 < N) { al_s[(r0 + 3) * 2 + head] = vs3; al_d[(r0 + 3) * 2 + head] = vd3; }
    }
}

// -- stage 2: per-segment LDS counting sort (wave-scan version, round-9) ----
__global__ __launch_bounds__(1024) void sortseg(
    const int* __restrict__ segcnt, int N,
    unsigned* __restrict__ part, int* __restrict__ nodeofs, int* __restrict__ cnt,
    int* __restrict__ perm) {
    __shared__ int h2[4096];
    __shared__ int ex[256];
    __shared__ int wsum[4];
    __shared__ unsigned outb[SEGCAP];
    int b = blockIdx.x, t = threadIdx.x;
    int lane = t & 63;
    size_t base = (size_t)b * SEGCAP;
    int sz = min(segcnt[b * 16], SEGCAP);
    for (int i = t; i < 4096; i += 1024) h2[i] = 0;
    __syncthreads();
    for (int i = t; i < sz; i += 1024) {
        unsigned code = part[base + i];
        int key = ((code & 255) << 4) | ((code >> 21) & 15);
        atomicAdd(&h2[key], 1);
    }
    __syncthreads();
    int v = 0;
    if (t < 256) {
#pragma unroll
        for (int i = 0; i < 16; i++) v += h2[t * 16 + i];
    }
    // wave-level inclusive scan (t<256 lives in waves 0..3)
    int incl = v;
#pragma unroll
    for (int off = 1; off < 64; off <<= 1) {
        int y = __shfl_up(incl, off);
        if (lane >= off) incl += y;
    }
    if (t < 256 && lane == 63) wsum[t >> 6] = incl;
    __syncthreads();
    if (t < 256) {
        int w = t >> 6;
        int wpre = 0;
#pragma unroll
        for (int k = 0; k < 4; k++) if (k < w) wpre += wsum[k];
        int exv = incl + wpre - v;       // exclusive prefix
        int run = exv;
#pragma unroll
        for (int i = 0; i < 16; i++) {
            int lc = h2[t * 16 + i];
            h2[t * 16 + i] = run;
            run += lc;
        }
        int n = b * 256 + t;
        if (n < N) { cnt[n] = v; nodeofs[n] = (int)(base + exv); }
    }
    __syncthreads();
    for (int i = t; i < sz; i += 1024) {
        unsigned code = part[base + i];
        int key = ((code & 255) << 4) | ((code >> 21) & 15);
        int p = atomicAdd(&h2[key], 1);
        outb[p] = code >> 8;          // src
    }
    __syncthreads();
    for (int i = t; i < sz; i += 1024) part[base + i] = outb[i];
    // ---- segment-local degree sort -> perm (lanes < 256) ----
    __syncthreads();
    if (t < 256) h2[t] = 0;
    __syncthreads();
    int n = b * 256 + t;
    int dbin = min(v, 255);
    if (t < 256 && n < N) atomicAdd(&h2[dbin], 1);
    __syncthreads();
    int hv = (t < 256) ? h2[t] : 0;
    int incl2 = hv;
#pragma unroll
    for (int off = 1; off < 64; off <<= 1) {
        int y = __shfl_up(incl2, off);
        if (lane >= off) incl2 += y;
    }
    if (t < 256 && lane == 63) wsum[t >> 6] = incl2;
    __syncthreads();
    if (t < 256) {
        int w = t >> 6;
        int wpre = 0;
#pragma unroll
        for (int k = 0; k < 4; k++) if (k < w) wpre += wsum[k];
        ex[t] = incl2 + wpre - hv;       // exclusive prefix
    }
    __syncthreads();
    if (t < 256 && n < N) {
        int r = atomicAdd(&ex[dbin], 1);
        perm[b * 256 + r] = n;
    }
}

// -- layer1 aggregation + LN + ELU + FUSED prep2 GEMM (round-8 verified) ----
__global__ __launch_bounds__(256) void aggB1(
    const ushort* __restrict__ h1b, const float* __restrict__ als,
    const float* __restrict__ ald, const int* __restrict__ nodeofs,
    const int* __restrict__ cnt, const unsigned* __restrict__ csr,
    const int* __restrict__ perm,
    const float* __restrict__ b1, const float* __restrict__ g1,
    const float* __restrict__ bb1,
    const float* __restrict__ W2, const float* __restrict__ as2,
    const float* __restrict__ ad2, ushort* __restrict__ h2b,
    float* __restrict__ al2s, float* __restrict__ al2d, int N) {
    __shared__ uint4 stage[4][AG1_SLOTS * 64];   // 32 KiB: per-wave private
    __shared__ float W2s[64 * 32];               // 8 KiB
    int t = threadIdx.x;
    for (int i = t; i < 2048; i += 256) W2s[i] = W2[i];
    __syncthreads();
    int wid = t >> 6, lane = t & 63;
    int grp = lane >> 3, q = lane & 7;        // 8 lanes per node, lane holds ch [8q,8q+8)
    int gbase = grp << 3;
    uint4* mystage = stage[wid];
    int idx = blockIdx.x * 32 + wid * 8 + grp;
    bool valid = idx < N;
    int nc = perm[min(idx, N - 1)];
    int head = q >> 2;                        // ch<32 -> head0, ch>=32 -> head1
    const float2* als2 = (const float2*)als;
    const float2* ald2 = (const float2*)ald;
    float2 adv = ald2[nc], asv = als2[nc];
    float ad0 = adv.x, ad1v = adv.y;
    float wsf = __expf(leaky((head ? asv.y : asv.x) + (head ? ad1v : ad0)));
    const uint4* h4 = (const uint4*)h1b;      // 8 uint4 per 64-ch row
    uint4 hs = h4[(size_t)nc * 8 + q];
    float a0 = wsf * blo(hs.x), a1 = wsf * bhi(hs.x);
    float a2 = wsf * blo(hs.y), a3 = wsf * bhi(hs.y);
    float a4 = wsf * blo(hs.z), a5 = wsf * bhi(hs.z);
    float a6 = wsf * blo(hs.w), a7 = wsf * bhi(hs.w);
    float lp0 = 0.f, lp1 = 0.f;
    int ofs = valid ? nodeofs[nc] : 0;
    int deg = valid ? cnt[nc] : 0;
    int degm1 = max(deg - 1, 0);
    int degmax = deg;                          // deg near-uniform within wave (perm-sorted)
    degmax = max(degmax, __shfl_xor(degmax, 8));
    degmax = max(degmax, __shfl_xor(degmax, 16));
    degmax = max(degmax, __shfl_xor(degmax, 32));
    int sq = 0;
    if (degmax > 0) sq = min((int)csr[ofs + min(q, degm1)], N - 1);
    for (int eb = 0; eb < degmax; eb += AG1_SLOTS) {
#pragma unroll
        for (int k = 0; k < AG1_SLOTS; k++) {
            int s = __shfl(sq, gbase + k);
            gather16_to_lds(h4 + ((size_t)s * 8 + q), &mystage[k * 64]);
        }
        float2 av = als2[sq];
        int nsq = sq;
        int ebn = eb + AG1_SLOTS;
        if (ebn < degmax)
            nsq = min((int)csr[ofs + min(ebn + q, degm1)], N - 1);
        bool ev = (eb + q < deg);
        float w0 = ev ? __expf(leaky(av.x + ad0)) : 0.f;
        float w1 = ev ? __expf(leaky(av.y + ad1v)) : 0.f;
        lp0 += w0;
        lp1 += w1;
        asm volatile("s_waitcnt vmcnt(0)" ::: "memory");
        __builtin_amdgcn_sched_barrier(0);
#pragma unroll
        for (int k = 0; k < AG1_SLOTS; k++) {
            float wk0 = __shfl(w0, gbase + k);
            float wk1 = __shfl(w1, gbase + k);
            float w = head ? wk1 : wk0;
            uint4 hv = mystage[k * 64 + lane];   // contiguous: conflict-free b128
            a0 = fmaf(w, blo(hv.x), a0); a1 = fmaf(w, bhi(hv.x), a1);
            a2 = fmaf(w, blo(hv.y), a2); a3 = fmaf(w, bhi(hv.y), a3);
            a4 = fmaf(w, blo(hv.z), a4); a5 = fmaf(w, bhi(hv.z), a5);
            a6 = fmaf(w, blo(hv.w), a6); a7 = fmaf(w, bhi(hv.w), a7);
        }
        sq = nsq;
    }
#pragma unroll
    for (int off = 1; off < 8; off <<= 1) {
        lp0 += __shfl_xor(lp0, off);
        lp1 += __shfl_xor(lp1, off);
    }
    if (!valid) return;
    float l = (head ? lp1 : lp0) + wsf;
    float inv = 1.f / l;
    float4 bA = ((const float4*)b1)[2 * q];
    float4 bB = ((const float4*)b1)[2 * q + 1];
    float v0 = a0 * inv + bA.x, v1 = a1 * inv + bA.y;
    float v2 = a2 * inv + bA.z, v3 = a3 * inv + bA.w;
    float v4 = a4 * inv + bB.x, v5 = a5 * inv + bB.y;
    float v6 = a6 * inv + bB.z, v7 = a7 * inv + bB.w;
    float s1 = v0 + v1 + v2 + v3 + v4 + v5 + v6 + v7;
#pragma unroll
    for (int off = 1; off < 8; off <<= 1) s1 += __shfl_xor(s1, off);
    float mu = s1 * (1.f / 64.f);
    float d0 = v0 - mu, d1 = v1 - mu, d2 = v2 - mu, d3 = v3 - mu;
    float d4 = v4 - mu, d5 = v5 - mu, d6 = v6 - mu, d7 = v7 - mu;
    float s2v = d0 * d0 + d1 * d1 + d2 * d2 + d3 * d3
              + d4 * d4 + d5 * d5 + d6 * d6 + d7 * d7;
#pragma unroll
    for (int off = 1; off < 8; off <<= 1) s2v += __shfl_xor(s2v, off);
    float rs = rsqrtf(s2v * (1.f / 64.f) + EPS);
    float4 gA = ((const float4*)g1)[2 * q];
    float4 gB = ((const float4*)g1)[2 * q + 1];
    float4 cA = ((const float4*)bb1)[2 * q];
    float4 cB = ((const float4*)bb1)[2 * q + 1];
    float ya[8];
    ya[0] = d0 * rs * gA.x + cA.x;
    ya[1] = d1 * rs * gA.y + cA.y;
    ya[2] = d2 * rs * gA.z + cA.z;
    ya[3] = d3 * rs * gA.w + cA.w;
    ya[4] = d4 * rs * gB.x + cB.x;
    ya[5] = d5 * rs * gB.y + cB.y;
    ya[6] = d6 * rs * gB.z + cB.z;
    ya[7] = d7 * rs * gB.w + cB.w;
#pragma unroll
    for (int j = 0; j < 8; j++)
        ya[j] = (ya[j] > 0.f) ? ya[j] : (__expf(ya[j]) - 1.f);
    // ---- fused prep2: lane q computes h2 channels 4q..4q+3 ----
    float o0 = 0.f, o1 = 0.f, o2 = 0.f, o3 = 0.f;
#pragma unroll
    for (int src = 0; src < 8; src++) {
#pragma unroll
        for (int j = 0; j < 8; j++) {
            float yv = __shfl(ya[j], gbase + src);
            float4 wr = *(const float4*)&W2s[(src * 8 + j) * 32 + 4 * q];
            o0 = fmaf(yv, wr.x, o0);
            o1 = fmaf(yv, wr.y, o1);
            o2 = fmaf(yv, wr.z, o2);
            o3 = fmaf(yv, wr.w, o3);
        }
    }
    ((ushort4*)h2b)[(size_t)nc * 8 + q] =
        make_ushort4(f2bf(o0), f2bf(o1), f2bf(o2), f2bf(o3));
    float4 a2v = ((const float4*)as2)[q];
    float4 d2v = ((const float4*)ad2)[q];
    float ps = o0 * a2v.x + o1 * a2v.y + o2 * a2v.z + o3 * a2v.w;
    float pd = o0 * d2v.x + o1 * d2v.y + o2 * d2v.z + o3 * d2v.w;
    ps += __shfl_xor(ps, 1); ps += __shfl_xor(ps, 2); ps += __shfl_xor(ps, 4);
    pd += __shfl_xor(pd, 1); pd += __shfl_xor(pd, 2); pd += __shfl_xor(pd, 4);
    if (q == 0) { al2s[nc] = ps; al2d[nc] = pd; }
}

// -- layer2 aggregation: pipelined 16-edge batches, staged gathers ----------
__global__ __launch_bounds__(256, 2) void aggB2(
    const ushort* __restrict__ h2b, const float* __restrict__ als,
    const float* __restrict__ ald, const int* __restrict__ nodeofs,
    const int* __restrict__ cnt, const unsigned* __restrict__ csr,
    const int* __restrict__ perm,
    const float* __restrict__ b2, const float* __restrict__ g2,
    const float* __restrict__ bb2, const float* __restrict__ Wout,
    const float* __restrict__ bout, float* __restrict__ out, int N) {
    int lane = threadIdx.x & 63;
    int grp = lane >> 3, q = lane & 7;
    int gbase = grp << 3;
    int idx = blockIdx.x * 32 + (threadIdx.x >> 6) * 8 + grp;
    bool valid = idx < N;
    int nc = perm[min(idx, N - 1)];
    float myad = ald[nc];
    float wsf = __expf(leaky(als[nc] + myad));
    const ushort4* h4 = (const ushort4*)h2b;
    ushort4 hs = h4[(unsigned)nc * 8 + q];
    float a0 = wsf * bf2f(hs.x), a1 = wsf * bf2f(hs.y);
    float a2 = wsf * bf2f(hs.z), a3 = wsf * bf2f(hs.w);
    float lp = 0.f;
    int ofs = valid ? nodeofs[nc] : 0;
    int deg = valid ? cnt[nc] : 0;
    int degm1 = max(deg - 1, 0);
    int degmax = deg;              // uniform within 8-lane group
    degmax = max(degmax, __shfl_xor(degmax, 8));
    degmax = max(degmax, __shfl_xor(degmax, 16));
    degmax = max(degmax, __shfl_xor(degmax, 32));
    int sq0 = 0, sq1 = 0;
    if (degmax > 0) {
        int j0 = ofs + min(q, degm1);
        int j1 = ofs + min(8 + q, degm1);
        sq0 = min((int)csr[j0], N - 1);
        sq1 = min((int)csr[j1], N - 1);
    }
    for (int eb = 0; eb < degmax; eb += 16) {
        int s0[8], s1[8];
#pragma unroll
        for (int jj = 0; jj < 8; jj++) {
            s0[jj] = __shfl(sq0, gbase + jj);
            s1[jj] = __shfl(sq1, gbase + jj);
        }
        float av0 = als[sq0];
        float av1 = als[sq1];
        int nsq0 = sq0, nsq1 = sq1;
        int ebn = eb + 16;
        if (ebn < degmax) {
            int j0 = ofs + min(ebn + q, degm1);
            int j1 = ofs + min(ebn + 8 + q, degm1);
            nsq0 = min((int)csr[j0], N - 1);
            nsq1 = min((int)csr[j1], N - 1);
        }
        ushort4 r0[8], r1[8];
#pragma unroll
        for (int jj = 0; jj < 8; jj++) {
            r0[jj] = h4[(unsigned)s0[jj] * 8 + q];
            r1[jj] = h4[(unsigned)s1[jj] * 8 + q];
        }
        float z0 = leaky(av0 + myad);
        float z1 = leaky(av1 + myad);
        float wq0 = (eb + q < deg) ? __expf(z0) : 0.f;
        float wq1 = (eb + 8 + q < deg) ? __expf(z1) : 0.f;
        lp += wq0 + wq1;
        float w0a[8], w1a[8];
#pragma unroll
        for (int jj = 0; jj < 8; jj++) {
            w0a[jj] = __shfl(wq0, gbase + jj);
            w1a[jj] = __shfl(wq1, gbase + jj);
        }
#pragma unroll
        for (int jj = 0; jj < 8; jj++) {
            float w0 = w0a[jj], w1 = w1a[jj];
            a0 = fmaf(w0, bf2f(r0[jj].x), a0);
            a1 = fmaf(w0, bf2f(r0[jj].y), a1);
            a2 = fmaf(w0, bf2f(r0[jj].z), a2);
            a3 = fmaf(w0, bf2f(r0[jj].w), a3);
            a0 = fmaf(w1, bf2f(r1[jj].x), a0);
            a1 = fmaf(w1, bf2f(r1[jj].y), a1);
            a2 = fmaf(w1, bf2f(r1[jj].z), a2);
            a3 = fmaf(w1, bf2f(r1[jj].w), a3);
        }
        sq0 = nsq0;
        sq1 = nsq1;
    }
#pragma unroll
    for (int off = 1; off < 8; off <<= 1) lp += __shfl_xor(lp, off);
    if (!valid) return;
    float l = lp + wsf;
    float inv = 1.f / l;
    float4 bv = ((const float4*)b2)[q];
    float v0 = a0 * inv + bv.x, v1 = a1 * inv + bv.y;
    float v2 = a2 * inv + bv.z, v3 = a3 * inv + bv.w;
    float s1 = v0 + v1 + v2 + v3;
#pragma unroll
    for (int off = 1; off < 8; off <<= 1) s1 += __shfl_xor(s1, off);
    float mu = s1 * (1.f / 32.f);
    float d0 = v0 - mu, d1 = v1 - mu, d2 = v2 - mu, d3 = v3 - mu;
    float s2v = d0 * d0 + d1 * d1 + d2 * d2 + d3 * d3;
#pragma unroll
    for (int off = 1; off < 8; off <<= 1) s2v += __shfl_xor(s2v, off);
    float rs = rsqrtf(s2v * (1.f / 32.f) + EPS);
    float4 gv = ((const float4*)g2)[q];
    float4 bbv = ((const float4*)bb2)[q];
    float y0 = d0 * rs * gv.x + bbv.x;
    float y1 = d1 * rs * gv.y + bbv.y;
    float y2 = d2 * rs * gv.z + bbv.z;
    float y3 = d3 * rs * gv.w + bbv.w;
    y0 = (y0 > 0.f) ? y0 : (__expf(y0) - 1.f);
    y1 = (y1 > 0.f) ? y1 : (__expf(y1) - 1.f);
    y2 = (y2 > 0.f) ? y2 : (__expf(y2) - 1.f);
    y3 = (y3 > 0.f) ? y3 : (__expf(y3) - 1.f);
    float4 wo = ((const float4*)Wout)[q];
    float p = y0 * wo.x + y1 * wo.y + y2 * wo.z + y3 * wo.w;
#pragma unroll
    for (int off = 1; off < 8; off <<= 1) p += __shfl_xor(p, off);
    if (q == 0) out[nc] = p + bout[0];
}

extern "C" void kernel_launch(void* const* d_in, const int* in_sizes, int n_in,
                              void* d_out, int out_size, void* d_ws, size_t ws_size,
                              hipStream_t stream) {
    const float* x    = (const float*)d_in[0];
    const int*   ei   = (const int*)d_in[1];
    const float* W1   = (const float*)d_in[2];
    const float* as1  = (const float*)d_in[3];
    const float* ad1  = (const float*)d_in[4];
    const float* b1   = (const float*)d_in[5];
    const float* g1   = (const float*)d_in[6];
    const float* bb1  = (const float*)d_in[7];
    const float* W2   = (const float*)d_in[8];
    const float* as2  = (const float*)d_in[9];
    const float* ad2  = (const float*)d_in[10];
    const float* b2   = (const float*)d_in[11];
    const float* g2   = (const float*)d_in[12];
    const float* bb2  = (const float*)d_in[13];
    const float* Wout = (const float*)d_in[14];
    const float* bout = (const float*)d_in[15];
    float* out = (float*)d_out;

    const int N = in_sizes[0] / 64;
    const int E = in_sizes[1] / 2;
    const int K = (N + 255) / 256;   // segments (<= MAXK)

    auto align_up = [](size_t v) { return (v + 255) & ~(size_t)255; };
    char* ws = (char*)d_ws;
    unsigned* part    = (unsigned*)ws; ws += align_up((size_t)K * SEGCAP * 4);
    int*      segcnt  = (int*)ws;      ws += align_up((size_t)MAXK * 16 * 4);
    int*      nodeofs = (int*)ws;      ws += align_up((size_t)N * 4);
    int*      cnt     = (int*)ws;      ws += align_up((size_t)N * 4);
    int*      perm    = (int*)ws;      ws += align_up((size_t)(K * 256) * 4);
    ushort*   h1b     = (ushort*)ws;   ws += align_up((size_t)N * 64 * 2);
    ushort*   h2b     = (ushort*)ws;   ws += align_up((size_t)N * 32 * 2);
    float*    al1s    = (float*)ws;    ws += align_up((size_t)N * 2 * 4);
    float*    al1d    = (float*)ws;    ws += align_up((size_t)N * 2 * 4);
    float*    al2s    = (float*)ws;    ws += align_up((size_t)N * 4);
    float*    al2d    = (float*)ws;    ws += align_up((size_t)N * 4);

    const int EB = (E + PBATCH - 1) / PBATCH;
    const int PB = (N + 63) / 64;

    hipMemsetAsync(segcnt, 0, (size_t)K * 16 * 4, stream);
    fused1<<<EB + PB, 1024, 0, stream>>>(ei, E, K, segcnt, part,
                                         x, W1, as1, ad1, h1b, al1s, al1d, N, EB);
    sortseg<<<K, 1024, 0, stream>>>(segcnt, N, part, nodeofs, cnt, perm);
    aggB1<<<(N + 31) / 32, 256, 0, stream>>>(h1b, al1s, al1d, nodeofs, cnt, part,
                                             perm, b1, g1, bb1,
                                             W2, as2, ad2, h2b, al2s, al2d, N);
    aggB2<<<(N + 31) / 32, 256, 0, stream>>>(h2b, al2s, al2d, nodeofs, cnt, part,
                                             perm, b2, g2, bb2, Wout, bout, out, N);
}